// Round 13
// baseline (4261.160 us; speedup 1.0000x reference)
//
#include <hip/hip_runtime.h>
#include <hip/hip_bf16.h>

// ---------------------------------------------------------------------------
// GNN round 12 kernel (resubmitted unchanged after infra timeout).
// MFMA bf16x3 with pre-split operand planes.
// r11 diagnosis: occupancy 11.8% (1 wave/SIMD; VGPR 256 + AGPR > 256 alloc),
// inline fp32->bf16x3 split in the inner loop caused the pressure; fp32 LDS
// PAD=200 gave 4-way bank conflicts (7.2M); B-frags re-read per tile.
// Fixes: x pre-split once per node into planes (xhm=hi|mid<<16, xl);
// A staged in LDS as 3 bf16 planes (PAD=K+8 -> balanced banks); A-frag =
// 3x ds_read_b128, no split VALU in loop; activations split at write-back
// into the same planes (bit-identical math to r11 -> absmax should stay 0).
// LDS 76.8KB/block (KIN=192) -> 2 blocks/CU; target ~120 VGPR -> 8 waves/CU.
// In-place x/plane update by k_node (per-row ownership) saves the xb buffer.
// ---------------------------------------------------------------------------

typedef unsigned short ushort;
typedef unsigned int uint;
using bf16x8 = __attribute__((ext_vector_type(8))) short;
using f32x4 = __attribute__((ext_vector_type(4))) float;

__device__ __forceinline__ f32x4 mfma16(bf16x8 a, bf16x8 b, f32x4 c) {
    return __builtin_amdgcn_mfma_f32_16x16x32_bf16(a, b, c, 0, 0, 0);
}

__device__ __forceinline__ ushort f2bf(float x) {  // RNE to bf16 bits
    union { float f; uint u; } v;
    v.f = x;
    uint r = v.u + 0x7fffu + ((v.u >> 16) & 1u);
    return (ushort)(r >> 16);
}
__device__ __forceinline__ float bf2f(ushort u) {
    union { uint u; float f; } v;
    v.u = ((uint)u) << 16;
    return v.f;
}

__device__ __forceinline__ float gelu(float x) {
    float x3 = x * x * x;
    return 0.5f * x * (1.f + tanhf(0.7978845608028654f * (x + 0.044715f * x3)));
}

__device__ __forceinline__ float wave_ln(float v, float lns, float lnb) {
    float s1 = v, s2 = v * v;
#pragma unroll
    for (int m = 32; m; m >>= 1) {
        s1 += __shfl_xor(s1, m, 64);
        s2 += __shfl_xor(s2, m, 64);
    }
    float mu = s1 * (1.f / 64.f);
    float var = s2 * (1.f / 64.f) - mu * mu;
    return (v - mu) * rsqrtf(var + 1e-6f) * lns + lnb;
}

// ---------------------------------------------------------------------------
// Weight prep: split W[K][64] into hi/mid/lo bf16, fragment order:
// idx = ((kc*4+hb)*64+lane)*8+j holds W[kc*32+8*(lane>>4)+j][hb*16+(lane&15)].
__global__ void k_prep(const float* __restrict__ W, ushort* __restrict__ dh,
                       ushort* __restrict__ dm, ushort* __restrict__ dl,
                       int K) {
    int tid = blockIdx.x * 256 + threadIdx.x;
    if (tid >= K * 64) return;
    int j = tid & 7;
    int lane = (tid >> 3) & 63;
    int hb = (tid >> 9) & 3;
    int kc = tid >> 11;
    int k = kc * 32 + 8 * (lane >> 4) + j;
    int h = hb * 16 + (lane & 15);
    float x = W[k * 64 + h];
    ushort uh = f2bf(x);
    float r = x - bf2f(uh);
    ushort um = f2bf(r);
    float r2 = r - bf2f(um);
    ushort ul = f2bf(r2);
    dh[tid] = uh;
    dm[tid] = um;
    dl[tid] = ul;
}

// ---------------------------------------------------------------------------
// One layer: D[16][64] += A[16][KC*32]*B. A: 3 bf16 LDS planes (stride pad),
// lane l reads row l&15, k-chunk kc, j=8*(l>>4)..+7. B: frag-ordered global.
template <int KC>
__device__ __forceinline__ void mfma_layer_p(
    const ushort* Ah, const ushort* Am, const ushort* Al, int pad,
    const ushort* __restrict__ Bh, const ushort* __restrict__ Bm,
    const ushort* __restrict__ Bl, int lane, f32x4 acc[4]) {
    int e15 = lane & 15, l4 = lane >> 4;
#pragma unroll
    for (int kc = 0; kc < KC; ++kc) {
        int ao = e15 * pad + kc * 32 + 8 * l4;
        bf16x8 ah = *reinterpret_cast<const bf16x8*>(Ah + ao);
        bf16x8 am = *reinterpret_cast<const bf16x8*>(Am + ao);
        bf16x8 al = *reinterpret_cast<const bf16x8*>(Al + ao);
#pragma unroll
        for (int hb = 0; hb < 4; ++hb) {
            int bi = ((kc * 4 + hb) * 64 + lane) * 8;
            bf16x8 bh_ = *reinterpret_cast<const bf16x8*>(Bh + bi);
            bf16x8 bm_ = *reinterpret_cast<const bf16x8*>(Bm + bi);
            bf16x8 bl_ = *reinterpret_cast<const bf16x8*>(Bl + bi);
            acc[hb] = mfma16(ah, bh_, acc[hb]);
            acc[hb] = mfma16(ah, bm_, acc[hb]);
            acc[hb] = mfma16(am, bh_, acc[hb]);
            acc[hb] = mfma16(ah, bl_, acc[hb]);
            acc[hb] = mfma16(am, bm_, acc[hb]);
            acc[hb] = mfma16(al, bh_, acc[hb]);
        }
    }
}

// ---------------------------------------------------------------------------
// Edge MLP. KIN=128 (step 0) / 192. A from pre-split x planes (+LN'd prev
// edge split inline). Activations split at write into the same LDS planes.
template <int KIN>
__global__ __launch_bounds__(256) void k_edge_mfma(
    const uint* __restrict__ xhm, const ushort* __restrict__ xl,
    float* __restrict__ eraw, const int* __restrict__ senders,
    const int* __restrict__ receivers, const ushort* __restrict__ B0h,
    const ushort* __restrict__ B0m, const ushort* __restrict__ B0l,
    const ushort* __restrict__ B1h, const ushort* __restrict__ B1m,
    const ushort* __restrict__ B1l, const ushort* __restrict__ B2h,
    const ushort* __restrict__ B2m, const ushort* __restrict__ B2l,
    const float* __restrict__ b0, const float* __restrict__ b1,
    const float* __restrict__ b2, const float* __restrict__ lnp_s,
    const float* __restrict__ lnp_b, int n_edges) {
    constexpr int KC0 = KIN / 32;
    constexpr int PAD = KIN + 8;  // bf16 elems; row stride 2*PAD B -> banks+4
    __shared__ ushort Ah[4][16 * PAD];
    __shared__ ushort Am[4][16 * PAD];
    __shared__ ushort Al[4][16 * PAD];
    int tid = threadIdx.x;
    int lane = tid & 63;
    int wsub = tid >> 6;
    ushort* ah_ = Ah[wsub];
    ushort* am_ = Am[wsub];
    ushort* al_ = Al[wsub];
    int e15 = lane & 15, l4 = lane >> 4;

    float plns = 0.f, plnb = 0.f;
    if constexpr (KIN == 192) {
        plns = lnp_s[lane];
        plnb = lnp_b[lane];
    }
    float bv0[4], bv1[4], bv2[4];
#pragma unroll
    for (int hb = 0; hb < 4; ++hb) {
        bv0[hb] = b0[hb * 16 + e15];
        bv1[hb] = b1[hb * 16 + e15];
        bv2[hb] = b2[hb * 16 + e15];
    }

    int wid = blockIdx.x * 4 + wsub;
    int nw = gridDim.x * 4;
    int ntiles = (n_edges + 15) >> 4;

    for (int t = wid; t < ntiles; t += nw) {
        int base = t << 4;
        // ---- stage 16 rows as bf16 planes ----
        for (int i = 0; i < 16; ++i) {
            int e = base + i;
            if (e < n_edges) {
                int snd = senders[e];
                int rcv = receivers[e];
                uint shm = xhm[(size_t)snd * 64 + lane];
                ushort sl = xl[(size_t)snd * 64 + lane];
                uint rhm = xhm[(size_t)rcv * 64 + lane];
                ushort rl = xl[(size_t)rcv * 64 + lane];
                int o = i * PAD;
                if constexpr (KIN == 192) {
                    float p = wave_ln(eraw[(size_t)e * 64 + lane], plns, plnb);
                    ushort ph = f2bf(p);
                    float pr = p - bf2f(ph);
                    ushort pm = f2bf(pr);
                    ushort pl = f2bf(pr - bf2f(pm));
                    ah_[o + lane] = ph;
                    am_[o + lane] = pm;
                    al_[o + lane] = pl;
                    ah_[o + 64 + lane] = (ushort)(shm & 0xffffu);
                    am_[o + 64 + lane] = (ushort)(shm >> 16);
                    al_[o + 64 + lane] = sl;
                    ah_[o + 128 + lane] = (ushort)(rhm & 0xffffu);
                    am_[o + 128 + lane] = (ushort)(rhm >> 16);
                    al_[o + 128 + lane] = rl;
                } else {
                    ah_[o + lane] = (ushort)(shm & 0xffffu);
                    am_[o + lane] = (ushort)(shm >> 16);
                    al_[o + lane] = sl;
                    ah_[o + 64 + lane] = (ushort)(rhm & 0xffffu);
                    am_[o + 64 + lane] = (ushort)(rhm >> 16);
                    al_[o + 64 + lane] = rl;
                }
            }
        }
        // ---- layer 1 ----
        f32x4 acc[4];
#pragma unroll
        for (int hb = 0; hb < 4; ++hb)
            acc[hb] = (f32x4){bv0[hb], bv0[hb], bv0[hb], bv0[hb]};
        mfma_layer_p<KC0>(ah_, am_, al_, PAD, B0h, B0m, B0l, lane, acc);
#pragma unroll
        for (int hb = 0; hb < 4; ++hb)
#pragma unroll
            for (int r = 0; r < 4; ++r) {
                float v = gelu(acc[hb][r]);
                ushort vh = f2bf(v);
                float vr = v - bf2f(vh);
                ushort vm = f2bf(vr);
                ushort vl = f2bf(vr - bf2f(vm));
                int o = (4 * l4 + r) * PAD + hb * 16 + e15;
                ah_[o] = vh;
                am_[o] = vm;
                al_[o] = vl;
            }
        // ---- layer 2 ----
#pragma unroll
        for (int hb = 0; hb < 4; ++hb)
            acc[hb] = (f32x4){bv1[hb], bv1[hb], bv1[hb], bv1[hb]};
        mfma_layer_p<2>(ah_, am_, al_, PAD, B1h, B1m, B1l, lane, acc);
#pragma unroll
        for (int hb = 0; hb < 4; ++hb)
#pragma unroll
            for (int r = 0; r < 4; ++r) {
                float v = gelu(acc[hb][r]);
                ushort vh = f2bf(v);
                float vr = v - bf2f(vh);
                ushort vm = f2bf(vr);
                ushort vl = f2bf(vr - bf2f(vm));
                int o = (4 * l4 + r) * PAD + hb * 16 + e15;
                ah_[o] = vh;
                am_[o] = vm;
                al_[o] = vl;
            }
        // ---- layer 3 -> raw edge store ----
#pragma unroll
        for (int hb = 0; hb < 4; ++hb)
            acc[hb] = (f32x4){bv2[hb], bv2[hb], bv2[hb], bv2[hb]};
        mfma_layer_p<2>(ah_, am_, al_, PAD, B2h, B2m, B2l, lane, acc);
#pragma unroll
        for (int hb = 0; hb < 4; ++hb)
#pragma unroll
            for (int r = 0; r < 4; ++r) {
                int e = base + 4 * l4 + r;
                if (e < n_edges)
                    eraw[(size_t)e * 64 + hb * 16 + e15] = acc[hb][r];
            }
    }
}

// ---------------------------------------------------------------------------
// Node MLP: CSR gather-sum (fp32) + x planes -> 3 layers -> LN -> x (in
// place, fp32 + planes). Per-row ownership makes in-place safe.
__global__ __launch_bounds__(256) void k_node_mfma(
    float* __restrict__ x, uint* __restrict__ xhm, ushort* __restrict__ xl,
    const float* __restrict__ eraw, const int* __restrict__ row_start,
    const int* __restrict__ elist, const ushort* __restrict__ B0h,
    const ushort* __restrict__ B0m, const ushort* __restrict__ B0l,
    const ushort* __restrict__ B1h, const ushort* __restrict__ B1m,
    const ushort* __restrict__ B1l, const ushort* __restrict__ B2h,
    const ushort* __restrict__ B2m, const ushort* __restrict__ B2l,
    const float* __restrict__ b0, const float* __restrict__ b1,
    const float* __restrict__ b2, const float* __restrict__ ln_s,
    const float* __restrict__ ln_b, int n) {
    constexpr int PAD = 136;
    __shared__ ushort Ah[4][16 * PAD];
    __shared__ ushort Am[4][16 * PAD];
    __shared__ ushort Al[4][16 * PAD];
    int tid = threadIdx.x;
    int lane = tid & 63;
    int wsub = tid >> 6;
    ushort* ah_ = Ah[wsub];
    ushort* am_ = Am[wsub];
    ushort* al_ = Al[wsub];
    int e15 = lane & 15, l4 = lane >> 4;

    float bv0[4], bv1[4], bv2[4], lnsv[4], lnbv[4];
#pragma unroll
    for (int hb = 0; hb < 4; ++hb) {
        bv0[hb] = b0[hb * 16 + e15];
        bv1[hb] = b1[hb * 16 + e15];
        bv2[hb] = b2[hb * 16 + e15];
        lnsv[hb] = ln_s[hb * 16 + e15];
        lnbv[hb] = ln_b[hb * 16 + e15];
    }

    int wid = blockIdx.x * 4 + wsub;
    int nw = gridDim.x * 4;
    int ntiles = (n + 15) >> 4;

    for (int t = wid; t < ntiles; t += nw) {
        int base = t << 4;
        for (int i = 0; i < 16; ++i) {
            int v = base + i;
            if (v < n) {
                uint hm = xhm[(size_t)v * 64 + lane];
                ushort lo = xl[(size_t)v * 64 + lane];
                int o = i * PAD;
                ah_[o + lane] = (ushort)(hm & 0xffffu);
                am_[o + lane] = (ushort)(hm >> 16);
                al_[o + lane] = lo;
                int i0 = row_start[v], i1 = row_start[v + 1];
                float rv = 0.f, rv2 = 0.f;
                int ii = i0;
                for (; ii + 1 < i1; ii += 2) {
                    rv += eraw[(size_t)elist[ii] * 64 + lane];
                    rv2 += eraw[(size_t)elist[ii + 1] * 64 + lane];
                }
                if (ii < i1) rv += eraw[(size_t)elist[ii] * 64 + lane];
                rv += rv2;
                ushort rh = f2bf(rv);
                float rr = rv - bf2f(rh);
                ushort rm = f2bf(rr);
                ushort rl = f2bf(rr - bf2f(rm));
                ah_[o + 64 + lane] = rh;
                am_[o + 64 + lane] = rm;
                al_[o + 64 + lane] = rl;
            }
        }
        f32x4 acc[4];
#pragma unroll
        for (int hb = 0; hb < 4; ++hb)
            acc[hb] = (f32x4){bv0[hb], bv0[hb], bv0[hb], bv0[hb]};
        mfma_layer_p<4>(ah_, am_, al_, PAD, B0h, B0m, B0l, lane, acc);
#pragma unroll
        for (int hb = 0; hb < 4; ++hb)
#pragma unroll
            for (int r = 0; r < 4; ++r) {
                float v = gelu(acc[hb][r]);
                ushort vh = f2bf(v);
                float vr = v - bf2f(vh);
                ushort vm = f2bf(vr);
                ushort vl = f2bf(vr - bf2f(vm));
                int o = (4 * l4 + r) * PAD + hb * 16 + e15;
                ah_[o] = vh;
                am_[o] = vm;
                al_[o] = vl;
            }
#pragma unroll
        for (int hb = 0; hb < 4; ++hb)
            acc[hb] = (f32x4){bv1[hb], bv1[hb], bv1[hb], bv1[hb]};
        mfma_layer_p<2>(ah_, am_, al_, PAD, B1h, B1m, B1l, lane, acc);
#pragma unroll
        for (int hb = 0; hb < 4; ++hb)
#pragma unroll
            for (int r = 0; r < 4; ++r) {
                float v = gelu(acc[hb][r]);
                ushort vh = f2bf(v);
                float vr = v - bf2f(vh);
                ushort vm = f2bf(vr);
                ushort vl = f2bf(vr - bf2f(vm));
                int o = (4 * l4 + r) * PAD + hb * 16 + e15;
                ah_[o] = vh;
                am_[o] = vm;
                al_[o] = vl;
            }
#pragma unroll
        for (int hb = 0; hb < 4; ++hb)
            acc[hb] = (f32x4){bv2[hb], bv2[hb], bv2[hb], bv2[hb]};
        mfma_layer_p<2>(ah_, am_, al_, PAD, B2h, B2m, B2l, lane, acc);
        // LayerNorm across h (16-lane groups hold one node row in cols)
        float s1[4] = {0.f, 0.f, 0.f, 0.f}, s2[4] = {0.f, 0.f, 0.f, 0.f};
#pragma unroll
        for (int hb = 0; hb < 4; ++hb)
#pragma unroll
            for (int r = 0; r < 4; ++r) {
                float vv = acc[hb][r];
                s1[r] += vv;
                s2[r] += vv * vv;
            }
#pragma unroll
        for (int m = 1; m <= 8; m <<= 1)
#pragma unroll
            for (int r = 0; r < 4; ++r) {
                s1[r] += __shfl_xor(s1[r], m, 64);
                s2[r] += __shfl_xor(s2[r], m, 64);
            }
#pragma unroll
        for (int r = 0; r < 4; ++r) {
            int v = base + 4 * l4 + r;
            if (v < n) {
                float mu = s1[r] * (1.f / 64.f);
                float var = s2[r] * (1.f / 64.f) - mu * mu;
                float rs = rsqrtf(var + 1e-6f);
#pragma unroll
                for (int hb = 0; hb < 4; ++hb) {
                    float y = (acc[hb][r] - mu) * rs * lnsv[hb] + lnbv[hb];
                    size_t idx = (size_t)v * 64 + hb * 16 + e15;
                    x[idx] = y;
                    ushort yh = f2bf(y);
                    float yr = y - bf2f(yh);
                    ushort ym = f2bf(yr);
                    ushort yl2 = f2bf(yr - bf2f(ym));
                    xhm[idx] = (uint)yh | ((uint)ym << 16);
                    xl[idx] = yl2;
                }
            }
        }
    }
}

// ---------------------------------------------------------------------------
// CSR construction (unchanged, validated)
__global__ void k_hist(const int* __restrict__ receivers, int* __restrict__ cnt,
                       int nE) {
    int e = blockIdx.x * blockDim.x + threadIdx.x;
    if (e < nE) atomicAdd(&cnt[receivers[e]], 1);
}

__global__ void k_scan1(const int* __restrict__ cnt, int* __restrict__ bsum,
                        int n) {
    __shared__ int sb[256];
    int t = threadIdx.x;
    int i = blockIdx.x * 256 + t;
    sb[t] = (i < n) ? cnt[i] : 0;
    __syncthreads();
    for (int off = 128; off; off >>= 1) {
        if (t < off) sb[t] += sb[t + off];
        __syncthreads();
    }
    if (t == 0) bsum[blockIdx.x] = sb[0];
}

__global__ void k_scan2(int* __restrict__ bsum, int nb) {
    __shared__ int sb[256];
    int t = threadIdx.x;
    int v = (t < nb) ? bsum[t] : 0;
    sb[t] = v;
    __syncthreads();
    for (int off = 1; off < 256; off <<= 1) {
        int add = (t >= off) ? sb[t - off] : 0;
        __syncthreads();
        sb[t] += add;
        __syncthreads();
    }
    if (t < nb) bsum[t] = sb[t] - v;  // exclusive
}

__global__ void k_scan3(const int* __restrict__ cnt, const int* __restrict__ bsum,
                        int* __restrict__ row_start, int* __restrict__ cursor,
                        int n, int nE) {
    __shared__ int sb[256];
    int t = threadIdx.x;
    int i = blockIdx.x * 256 + t;
    int v = (i < n) ? cnt[i] : 0;
    sb[t] = v;
    __syncthreads();
    for (int off = 1; off < 256; off <<= 1) {
        int add = (t >= off) ? sb[t - off] : 0;
        __syncthreads();
        sb[t] += add;
        __syncthreads();
    }
    if (i < n) {
        int ex = bsum[blockIdx.x] + sb[t] - v;
        row_start[i] = ex;
        cursor[i] = ex;
    }
    if (i == n - 1) row_start[n] = nE;
}

__global__ void k_fill(const int* __restrict__ receivers, int* __restrict__ cursor,
                       int* __restrict__ elist, int nE) {
    int e = blockIdx.x * blockDim.x + threadIdx.x;
    if (e < nE) {
        int r = receivers[e];
        int p = atomicAdd(&cursor[r], 1);
        elist[p] = e;
    }
}

// ---------------------------------------------------------------------------
// Embed: x = nodes @ W_emb + b; writes fp32 x AND split planes.
__global__ void k_embed(const float* __restrict__ nodes,
                        const float* __restrict__ W, const float* __restrict__ b,
                        float* __restrict__ x, uint* __restrict__ xhm,
                        ushort* __restrict__ xl, int n) {
    int lane = threadIdx.x & 63;
    int wid = blockIdx.x * 4 + (threadIdx.x >> 6);
    int nw = gridDim.x * 4;
    float wcol[7];
#pragma unroll
    for (int k = 0; k < 7; ++k) wcol[k] = W[k * 64 + lane];
    float bh = b[lane];
    for (int v = wid; v < n; v += nw) {
        float acc = bh;
#pragma unroll
        for (int k = 0; k < 7; ++k) acc = fmaf(nodes[v * 7 + k], wcol[k], acc);
        size_t idx = (size_t)v * 64 + lane;
        x[idx] = acc;
        ushort h = f2bf(acc);
        float r = acc - bf2f(h);
        ushort m = f2bf(r);
        ushort l = f2bf(r - bf2f(m));
        xhm[idx] = (uint)h | ((uint)m << 16);
        xl[idx] = l;
    }
}

__global__ void k_mean(const float* __restrict__ x, float* __restrict__ agg,
                       int n) {
    int t = threadIdx.x;
    int h = t & 63;
    int sub = t >> 6;
    float s = 0.f;
    for (int v = blockIdx.x * 4 + sub; v < n; v += gridDim.x * 4)
        s += x[(size_t)v * 64 + h];
    __shared__ float buf[256];
    buf[t] = s;
    __syncthreads();
    if (t < 64) {
        float tot = buf[t] + buf[t + 64] + buf[t + 128] + buf[t + 192];
        atomicAdd(&agg[h], tot);
    }
}

__global__ void k_readout(const float* __restrict__ agg,
                          const float* __restrict__ W1, const float* __restrict__ b1,
                          const float* __restrict__ W2, const float* __restrict__ b2,
                          const float* __restrict__ W3, const float* __restrict__ b3,
                          const float* __restrict__ W4, const float* __restrict__ b4,
                          float* __restrict__ out, float inv_n) {
    __shared__ float sA[64], sH1[256], sH2[128], sH3[128];
    int t = threadIdx.x;
    if (t < 64) sA[t] = agg[t] * inv_n;
    __syncthreads();
    {
        float acc = b1[t];
#pragma unroll
        for (int k = 0; k < 64; ++k) acc = fmaf(sA[k], W1[k * 256 + t], acc);
        sH1[t] = gelu(acc);
    }
    __syncthreads();
    if (t < 128) {
        float acc = b2[t];
        for (int k = 0; k < 256; ++k) acc = fmaf(sH1[k], W2[k * 128 + t], acc);
        sH2[t] = gelu(acc);
    }
    __syncthreads();
    if (t < 128) {
        float acc = b3[t];
        for (int k = 0; k < 128; ++k) acc = fmaf(sH2[k], W3[k * 128 + t], acc);
        sH3[t] = gelu(acc);
    }
    __syncthreads();
    if (t < 64) {
        float p = fmaf(sH3[t], W4[t], sH3[t + 64] * W4[t + 64]);
#pragma unroll
        for (int m = 32; m; m >>= 1) p += __shfl_xor(p, m, 64);
        if (t == 0) out[0] = p + b4[0];
    }
}

// ---------------------------------------------------------------------------
extern "C" void kernel_launch(void* const* d_in, const int* in_sizes, int n_in,
                              void* d_out, int out_size, void* d_ws,
                              size_t ws_size, hipStream_t stream) {
    const float* nodes = (const float*)d_in[0];
    const int* senders = (const int*)d_in[1];
    const int* receivers = (const int*)d_in[2];
    const float* W_emb = (const float*)d_in[3];
    const float* b_emb = (const float*)d_in[4];
    const float* eW0_first = (const float*)d_in[5];
    const float* eW0_rest = (const float*)d_in[6];
    const float* eW_hid = (const float*)d_in[7];
    const float* eb = (const float*)d_in[8];
    const float* nW0 = (const float*)d_in[9];
    const float* nW_hid = (const float*)d_in[10];
    const float* nb = (const float*)d_in[11];
    const float* ln_ns = (const float*)d_in[12];
    const float* ln_nb = (const float*)d_in[13];
    const float* ln_es = (const float*)d_in[14];
    const float* ln_eb = (const float*)d_in[15];
    const float* rW1 = (const float*)d_in[16];
    const float* rb1 = (const float*)d_in[17];
    const float* rW2 = (const float*)d_in[18];
    const float* rb2 = (const float*)d_in[19];
    const float* rW3 = (const float*)d_in[20];
    const float* rb3 = (const float*)d_in[21];
    const float* rW4 = (const float*)d_in[22];
    const float* rb4 = (const float*)d_in[23];

    const int N = in_sizes[0] / 7;  // 50000
    const int E = in_sizes[1];      // 800000

    float* ws = (float*)d_ws;
    float* eraw = ws;                          // E*64 f32
    float* x = eraw + (size_t)E * 64;          // N*64 f32 (in-place updated)
    float* agg = x + (size_t)N * 64;           // 64
    int* cnt = (int*)(agg + 64);               // N
    int* row_start = cnt + N;                  // N+1
    int* cursor = row_start + N + 1;           // N
    int* elist = cursor + N;                   // E
    int* bsum = elist + E;                     // 256
    const int WTOT = 106496;                   // split-weight elems per plane
    ushort* wfh = (ushort*)(bsum + 256);
    ushort* wfm = wfh + WTOT;
    ushort* wfl = wfm + WTOT;
    uint* xhm = (uint*)(wfl + WTOT);           // N*64 u32 (hi|mid<<16)
    ushort* xl = (ushort*)(xhm + (size_t)N * 64);  // N*64 u16

    const int OFF_E0 = 0;       // eW0_first K=128
    const int OFF_E1 = 8192;    // eW0_rest[0] K=192
    const int OFF_E2 = 20480;   // eW0_rest[1] K=192
    const int OFF_EH = 32768;   // eW_hid K=64 x6
    const int OFF_N0 = 57344;   // nW0 K=128 x3
    const int OFF_NH = 81920;   // nW_hid K=64 x6

    // ---- weight prep ----
    k_prep<<<32, 256, 0, stream>>>(eW0_first, wfh + OFF_E0, wfm + OFF_E0,
                                   wfl + OFF_E0, 128);
    k_prep<<<48, 256, 0, stream>>>(eW0_rest, wfh + OFF_E1, wfm + OFF_E1,
                                   wfl + OFF_E1, 192);
    k_prep<<<48, 256, 0, stream>>>(eW0_rest + (size_t)192 * 64, wfh + OFF_E2,
                                   wfm + OFF_E2, wfl + OFF_E2, 192);
    for (int i = 0; i < 6; ++i) {
        k_prep<<<16, 256, 0, stream>>>(eW_hid + (size_t)i * 4096,
                                       wfh + OFF_EH + i * 4096,
                                       wfm + OFF_EH + i * 4096,
                                       wfl + OFF_EH + i * 4096, 64);
        k_prep<<<16, 256, 0, stream>>>(nW_hid + (size_t)i * 4096,
                                       wfh + OFF_NH + i * 4096,
                                       wfm + OFF_NH + i * 4096,
                                       wfl + OFF_NH + i * 4096, 64);
    }
    for (int s = 0; s < 3; ++s)
        k_prep<<<32, 256, 0, stream>>>(nW0 + (size_t)s * 8192,
                                       wfh + OFF_N0 + s * 8192,
                                       wfm + OFF_N0 + s * 8192,
                                       wfl + OFF_N0 + s * 8192, 128);

    const int nb_scan = (N + 255) / 256;

    // ---- CSR build ----
    hipMemsetAsync(cnt, 0, (size_t)N * sizeof(int), stream);
    k_hist<<<(E + 255) / 256, 256, 0, stream>>>(receivers, cnt, E);
    k_scan1<<<nb_scan, 256, 0, stream>>>(cnt, bsum, N);
    k_scan2<<<1, 256, 0, stream>>>(bsum, nb_scan);
    k_scan3<<<nb_scan, 256, 0, stream>>>(cnt, bsum, row_start, cursor, N, E);
    k_fill<<<(E + 255) / 256, 256, 0, stream>>>(receivers, cursor, elist, E);

    k_embed<<<512, 256, 0, stream>>>(nodes, W_emb, b_emb, x, xhm, xl, N);

    for (int s = 0; s < 3; ++s) {
        int h1 = OFF_EH + (s * 2 + 0) * 4096;
        int h2 = OFF_EH + (s * 2 + 1) * 4096;
        const float* eb0 = eb + (s * 3 + 0) * 64;
        const float* eb1 = eb + (s * 3 + 1) * 64;
        const float* eb2 = eb + (s * 3 + 2) * 64;
        if (s == 0) {
            k_edge_mfma<128><<<1024, 256, 0, stream>>>(
                xhm, xl, eraw, senders, receivers, wfh + OFF_E0, wfm + OFF_E0,
                wfl + OFF_E0, wfh + h1, wfm + h1, wfl + h1, wfh + h2, wfm + h2,
                wfl + h2, eb0, eb1, eb2, nullptr, nullptr, E);
        } else {
            int w0 = (s == 1) ? OFF_E1 : OFF_E2;
            k_edge_mfma<192><<<1024, 256, 0, stream>>>(
                xhm, xl, eraw, senders, receivers, wfh + w0, wfm + w0,
                wfl + w0, wfh + h1, wfm + h1, wfl + h1, wfh + h2, wfm + h2,
                wfl + h2, eb0, eb1, eb2, ln_es + (s - 1) * 64,
                ln_eb + (s - 1) * 64, E);
        }
        int n1 = OFF_NH + (s * 2 + 0) * 4096;
        int n2 = OFF_NH + (s * 2 + 1) * 4096;
        int n0 = OFF_N0 + s * 8192;
        k_node_mfma<<<512, 256, 0, stream>>>(
            x, xhm, xl, eraw, row_start, elist, wfh + n0, wfm + n0, wfl + n0,
            wfh + n1, wfm + n1, wfl + n1, wfh + n2, wfm + n2, wfl + n2,
            nb + (s * 3 + 0) * 64, nb + (s * 3 + 1) * 64, nb + (s * 3 + 2) * 64,
            ln_ns + s * 64, ln_nb + s * 64, N);
    }

    hipMemsetAsync(agg, 0, 64 * sizeof(float), stream);
    k_mean<<<256, 256, 0, stream>>>(x, agg, N);
    k_readout<<<1, 256, 0, stream>>>(agg, rW1, rb1, rW2, rb2, rW3, rb3, rW4,
                                     rb4, (float*)d_out, 1.0f / (float)N);
}